// Round 6
// baseline (558.008 us; speedup 1.0000x reference)
//
#include <hip/hip_runtime.h>
#include <hip/hip_bf16.h>
#include <math.h>

#define NN 50000
#define NE 1600000
#define FIN 128
#define EH 20
#define DH 64

#define BSTEP 64                      // nodes per bucket
#define NBK ((NN + BSTEP - 1) / BSTEP)  // 782 buckets
#define CHUNK 4096                    // edges per k_bin block
#define PERT (CHUNK / 256)            // 16 edges per thread

// ---------------- kernels ----------------

// zero cnt and detect edge_index width (int64 vs int32)
__global__ void k_init(int* cnt, int* flag, const void* ei) {
    int i = blockIdx.x * blockDim.x + threadIdx.x;
    if (i < NN) cnt[i] = 0;
    if (i == 0) {
        const int* w = (const int*)ei;
        int all0 = 1;
        for (int j = 1; j < 128; j += 2) all0 &= (w[j] == 0);
        *flag = all0;  // 1 => int64 layout (high words zero), 0 => int32
    }
}

// convert edge_index to int32 r/c arrays and count in-degree of col
__global__ void k_cvt(const void* ei, const int* flag, int* r32, int* c32, int* cnt) {
    int e = blockIdx.x * blockDim.x + threadIdx.x;
    if (e >= NE) return;
    int r, c;
    if (*flag) {
        const long long* p = (const long long*)ei;
        r = (int)p[e];
        c = (int)p[NE + e];
    } else {
        const int* p = (const int*)ei;
        r = p[e];
        c = p[NE + e];
    }
    r32[e] = r;
    c32[e] = c;
    atomicAdd(&cnt[c], 1);
}

// single-block exclusive scan of cnt[NN] -> off[NN+1]; also init bucket cursors
__global__ void k_scan(const int* __restrict__ cnt, int* __restrict__ off,
                       int* __restrict__ bcur) {
    __shared__ int part[1024];
    const int t = threadIdx.x;
    const int CH = (NN + 1023) / 1024;  // 49
    const int base = t * CH;
    int s = 0;
    for (int i = 0; i < CH; ++i) {
        int idx = base + i;
        if (idx < NN) s += cnt[idx];
    }
    part[t] = s;
    __syncthreads();
    for (int d = 1; d < 1024; d <<= 1) {
        int v = 0;
        if (t >= d) v = part[t - d];
        __syncthreads();
        if (t >= d) part[t] += v;
        __syncthreads();
    }
    int excl = (t == 0) ? 0 : part[t - 1];
    for (int i = 0; i < CH; ++i) {
        int idx = base + i;
        if (idx < NN) {
            off[idx] = excl;
            excl += cnt[idx];
        }
    }
    if (t == 1023) off[NN] = excl;  // == NE
    __syncthreads();
    if (t < NBK) bcur[t] = off[t * BSTEP];
}

// two-level binned fill: packed records (r | c_local<<16) grouped by bucket.
__global__ void k_bin(const int* __restrict__ r32, const int* __restrict__ c32,
                      int* __restrict__ bcur, unsigned* __restrict__ binned) {
    __shared__ int hist[NBK];
    __shared__ int gbase[NBK];
    const int base = blockIdx.x * CHUNK;
    for (int i = threadIdx.x; i < NBK; i += 256) hist[i] = 0;
    __syncthreads();
    int myr[PERT], myc[PERT];
#pragma unroll
    for (int i = 0; i < PERT; ++i) {
        int idx = base + threadIdx.x + i * 256;
        if (idx < NE) {
            int r = r32[idx], c = c32[idx];
            myr[i] = r; myc[i] = c;
            atomicAdd(&hist[c >> 6], 1);
        } else {
            myc[i] = -1;
        }
    }
    __syncthreads();
    for (int b = threadIdx.x; b < NBK; b += 256) {
        int h = hist[b];
        gbase[b] = h ? atomicAdd(&bcur[b], h) : 0;
        hist[b] = 0;  // reuse as local cursor
    }
    __syncthreads();
#pragma unroll
    for (int i = 0; i < PERT; ++i) {
        int c = myc[i];
        if (c >= 0) {
            int bkt = c >> 6;
            int pos = gbase[bkt] + atomicAdd(&hist[bkt], 1);
            binned[pos] = (unsigned)myr[i] | ((unsigned)(c & 63) << 16);
        }
    }
}

// hs16[n*32+k] = bf16(dinv[n] * dot(x[n,:], W[:,k])) ; 20 lanes per node (64B rows)
__global__ void k_xw(const float* __restrict__ x, const float* __restrict__ W,
                     const int* __restrict__ cnt, __hip_bfloat16* __restrict__ hs16) {
    int t = blockIdx.x * blockDim.x + threadIdx.x;
    int n = t / EH;
    int k = t - n * EH;
    if (n >= NN) return;
    const float4* xr = (const float4*)(x + (size_t)n * FIN);
    float acc = 0.f;
#pragma unroll
    for (int j4 = 0; j4 < FIN / 4; ++j4) {
        float4 v = xr[j4];  // broadcast across the 20-lane group
        acc = fmaf(v.x, W[(4 * j4 + 0) * EH + k], acc);
        acc = fmaf(v.y, W[(4 * j4 + 1) * EH + k], acc);
        acc = fmaf(v.z, W[(4 * j4 + 2) * EH + k], acc);
        acc = fmaf(v.w, W[(4 * j4 + 3) * EH + k], acc);
    }
    float dinv = rsqrtf(1.0f + (float)cnt[n]);
    hs16[n * 32 + k] = __float2bfloat16(dinv * acc);
}

__device__ __forceinline__ float blo(unsigned u) { return __uint_as_float(u << 16); }
__device__ __forceinline__ float bhi(unsigned u) { return __uint_as_float(u & 0xffff0000u); }

// fused per-bucket gather: LDS accumulator tile, ds_add_f32, then bias+relu -> h1
__global__ void k_gath(const int* __restrict__ off, const unsigned* __restrict__ binned,
                       const int* __restrict__ cnt, const __hip_bfloat16* __restrict__ hs16,
                       const float* __restrict__ bg, float* __restrict__ h1) {
    __shared__ float acc[BSTEP * EH];  // 5.12 KB
    const int b = blockIdx.x;
    const int nbase = b * BSTEP;
    const int nend = min(nbase + BSTEP, NN);
    for (int i = threadIdx.x; i < BSTEP * EH; i += 256) acc[i] = 0.f;
    __syncthreads();
    const int p0 = off[nbase], p1 = off[nend];
    const unsigned short* hu = (const unsigned short*)hs16;
    for (int p = p0 + threadIdx.x; p < p1; p += 256) {
        unsigned rec = binned[p];
        int r = rec & 0xffffu;
        int cl = rec >> 16;
        const uint4* row = (const uint4*)(hu + (size_t)r * 32);
        uint4 v0 = row[0];
        uint4 v1 = row[1];
        uint2 v2 = *(const uint2*)(hu + (size_t)r * 32 + 16);
        float* a = acc + cl * EH;
        atomicAdd(&a[0],  blo(v0.x)); atomicAdd(&a[1],  bhi(v0.x));
        atomicAdd(&a[2],  blo(v0.y)); atomicAdd(&a[3],  bhi(v0.y));
        atomicAdd(&a[4],  blo(v0.z)); atomicAdd(&a[5],  bhi(v0.z));
        atomicAdd(&a[6],  blo(v0.w)); atomicAdd(&a[7],  bhi(v0.w));
        atomicAdd(&a[8],  blo(v1.x)); atomicAdd(&a[9],  bhi(v1.x));
        atomicAdd(&a[10], blo(v1.y)); atomicAdd(&a[11], bhi(v1.y));
        atomicAdd(&a[12], blo(v1.z)); atomicAdd(&a[13], bhi(v1.z));
        atomicAdd(&a[14], blo(v1.w)); atomicAdd(&a[15], bhi(v1.w));
        atomicAdd(&a[16], blo(v2.x)); atomicAdd(&a[17], bhi(v2.x));
        atomicAdd(&a[18], blo(v2.y)); atomicAdd(&a[19], bhi(v2.y));
    }
    __syncthreads();
    const int nloc = nend - nbase;
    for (int i = threadIdx.x; i < nloc * EH; i += 256) {
        int cl = i / EH;
        int k = i - cl * EH;
        int n = nbase + cl;
        float dinv = rsqrtf(1.0f + (float)cnt[n]);
        float self = blo((unsigned)hu[(size_t)n * 32 + k]);
        h1[(size_t)n * EH + k] = fmaxf(fmaf(dinv, self + acc[cl * EH + k], bg[k]), 0.f);
    }
}

// A16[n,j] = bf16(h1[n,:] @ W1[0:20, j]);
// B16[n,j] = bf16(b1[j] + h1[nid,:] @ W1[40:60, j] + h1[n,:] @ W1[20:40, j])
__global__ void k_ab(const float* __restrict__ h1, const float* __restrict__ W1,
                     const float* __restrict__ b1, const void* nid_p,
                     __hip_bfloat16* __restrict__ A16, __hip_bfloat16* __restrict__ B16) {
    int t = blockIdx.x * blockDim.x + threadIdx.x;
    int n = t >> 6;
    int j = t & 63;
    if (n >= NN) return;
    int nid = *(const int*)nid_p;  // low 32 bits valid for int32 or int64 LE
    const float* hr = h1 + (size_t)n * EH;
    const float* hn = h1 + (size_t)nid * EH;  // broadcast
    float a = 0.f, b = b1[j];
#pragma unroll
    for (int k = 0; k < EH; ++k) {
        float hv = hr[k];
        a = fmaf(hv, W1[k * DH + j], a);
        b = fmaf(hv, W1[(EH + k) * DH + j], b);
        b = fmaf(hn[k], W1[(2 * EH + k) * DH + j], b);
    }
    A16[(size_t)n * DH + j] = __float2bfloat16(a);
    B16[(size_t)n * DH + j] = __float2bfloat16(b);
}

// per-edge decoder: 1 thread per edge, edge order (sequential eps/out).
__global__ void k_edge(const int* __restrict__ r32, const int* __restrict__ c32,
                       const __hip_bfloat16* __restrict__ A16,
                       const __hip_bfloat16* __restrict__ B16,
                       const float* __restrict__ W2, const float* __restrict__ b2,
                       const float* __restrict__ eps, float* __restrict__ out) {
    int e = blockIdx.x * blockDim.x + threadIdx.x;
    if (e >= NE) return;
    int r = r32[e], c = c32[e];
    const uint4* arow = (const uint4*)(A16 + (size_t)r * DH);
    const uint4* brow = (const uint4*)(B16 + (size_t)c * DH);
    float acc = 0.f;
#pragma unroll
    for (int j = 0; j < 8; ++j) {
        uint4 av = arow[j];
        uint4 bv = brow[j];
        acc = fmaf(fmaxf(blo(av.x) + blo(bv.x), 0.f), W2[8 * j + 0], acc);
        acc = fmaf(fmaxf(bhi(av.x) + bhi(bv.x), 0.f), W2[8 * j + 1], acc);
        acc = fmaf(fmaxf(blo(av.y) + blo(bv.y), 0.f), W2[8 * j + 2], acc);
        acc = fmaf(fmaxf(bhi(av.y) + bhi(bv.y), 0.f), W2[8 * j + 3], acc);
        acc = fmaf(fmaxf(blo(av.z) + blo(bv.z), 0.f), W2[8 * j + 4], acc);
        acc = fmaf(fmaxf(bhi(av.z) + bhi(bv.z), 0.f), W2[8 * j + 5], acc);
        acc = fmaf(fmaxf(blo(av.w) + blo(bv.w), 0.f), W2[8 * j + 6], acc);
        acc = fmaf(fmaxf(bhi(av.w) + bhi(bv.w), 0.f), W2[8 * j + 7], acc);
    }
    float ep = eps[e];
    // e = (bias-(1-bias))*eps + (1-bias), bias=1e-4
    float ee = fmaf(-0.9998f, ep, 0.9999f);
    float gate = logf(ee) - log1pf(-ee) + acc + b2[0];
    out[e] = 1.0f / (1.0f + expf(-gate));
}

// ---------------- launch ----------------

extern "C" void kernel_launch(void* const* d_in, const int* in_sizes, int n_in,
                              void* d_out, int out_size, void* d_ws, size_t ws_size,
                              hipStream_t stream) {
    const float* x   = (const float*)d_in[0];
    const void*  ei  = d_in[1];
    const void*  nid = d_in[2];
    const float* eps = (const float*)d_in[3];
    const float* Wg  = (const float*)d_in[4];
    const float* bg  = (const float*)d_in[5];
    const float* W1  = (const float*)d_in[6];
    const float* b1  = (const float*)d_in[7];
    const float* W2  = (const float*)d_in[8];
    const float* b2  = (const float*)d_in[9];
    float* out = (float*)d_out;

    float* ws = (float*)d_ws;
    // Total ~9.3M floats ~= 37 MB, no aliasing.
    int*  r32    = (int*)(ws + 0);                            // 1.6M
    int*  c32    = (int*)(ws + 1600000);                      // 1.6M
    unsigned* binned = (unsigned*)(ws + 3200000);             // 1.6M
    __hip_bfloat16* hs16 = (__hip_bfloat16*)(ws + 4800000);   // 0.8M floats
    float* h1    = ws + 5600000;                              // 1.0M
    __hip_bfloat16* A16 = (__hip_bfloat16*)(ws + 6600000);    // 1.6M floats
    __hip_bfloat16* B16 = (__hip_bfloat16*)(ws + 8200000);    // 1.6M floats
    int* cnt     = (int*)(ws + 9800000);
    int* off     = (int*)(ws + 9851000);
    int* bcur    = (int*)(ws + 9902000);
    int* flag    = (int*)(ws + 9903000);

    dim3 blk(256);
    k_init<<<(NN + 255) / 256, blk, 0, stream>>>(cnt, flag, ei);
    k_cvt<<<(NE + 255) / 256, blk, 0, stream>>>(ei, flag, r32, c32, cnt);
    k_scan<<<1, 1024, 0, stream>>>(cnt, off, bcur);
    k_bin<<<(NE + CHUNK - 1) / CHUNK, blk, 0, stream>>>(r32, c32, bcur, binned);
    k_xw<<<(NN * EH + 255) / 256, blk, 0, stream>>>(x, Wg, cnt, hs16);
    k_gath<<<NBK, blk, 0, stream>>>(off, binned, cnt, hs16, bg, h1);
    k_ab<<<(NN * 64 + 255) / 256, blk, 0, stream>>>(h1, W1, b1, nid, A16, B16);
    k_edge<<<(NE + 255) / 256, blk, 0, stream>>>(r32, c32, A16, B16, W2, b2, eps, out);
}

// Round 7
// 380.026 us; speedup vs baseline: 1.4683x; 1.4683x over previous
//
#include <hip/hip_runtime.h>
#include <hip/hip_bf16.h>
#include <math.h>

#define NN 50000
#define NE 1600000
#define FIN 128
#define EH 20
#define DH 64

#define BSTEP 64                        // nodes per bucket
#define NBK ((NN + BSTEP - 1) / BSTEP)  // 782 buckets
#define CHUNK 4096                      // edges per k_bin block
#define PERT (CHUNK / 256)              // 16 edges per thread

// ---------------- kernels ----------------

// zero cnt and detect edge_index width (int64 vs int32)
__global__ void k_init(int* cnt, int* flag, const void* ei) {
    int i = blockIdx.x * blockDim.x + threadIdx.x;
    if (i < NN) cnt[i] = 0;
    if (i == 0) {
        const int* w = (const int*)ei;
        int all0 = 1;
        for (int j = 1; j < 128; j += 2) all0 &= (w[j] == 0);
        *flag = all0;  // 1 => int64 layout (high words zero), 0 => int32
    }
}

// convert edge_index to int32 r/c arrays and count in-degree of col
__global__ void k_cvt(const void* ei, const int* flag, int* r32, int* c32, int* cnt) {
    int e = blockIdx.x * blockDim.x + threadIdx.x;
    if (e >= NE) return;
    int r, c;
    if (*flag) {
        const long long* p = (const long long*)ei;
        r = (int)p[e];
        c = (int)p[NE + e];
    } else {
        const int* p = (const int*)ei;
        r = p[e];
        c = p[NE + e];
    }
    r32[e] = r;
    c32[e] = c;
    atomicAdd(&cnt[c], 1);
}

// single-block exclusive scan of cnt[NN] -> off[NN+1]; also init bucket cursors
__global__ void k_scan(const int* __restrict__ cnt, int* __restrict__ off,
                       int* __restrict__ bcur) {
    __shared__ int part[1024];
    const int t = threadIdx.x;
    const int CH = (NN + 1023) / 1024;  // 49
    const int base = t * CH;
    int s = 0;
    for (int i = 0; i < CH; ++i) {
        int idx = base + i;
        if (idx < NN) s += cnt[idx];
    }
    part[t] = s;
    __syncthreads();
    for (int d = 1; d < 1024; d <<= 1) {
        int v = 0;
        if (t >= d) v = part[t - d];
        __syncthreads();
        if (t >= d) part[t] += v;
        __syncthreads();
    }
    int excl = (t == 0) ? 0 : part[t - 1];
    for (int i = 0; i < CH; ++i) {
        int idx = base + i;
        if (idx < NN) {
            off[idx] = excl;
            excl += cnt[idx];
        }
    }
    if (t == 1023) off[NN] = excl;  // == NE
    __syncthreads();
    if (t < NBK) bcur[t] = off[t * BSTEP];
}

// two-level binned fill: packed records (r | c_local<<16) grouped by bucket.
__global__ void k_bin(const int* __restrict__ r32, const int* __restrict__ c32,
                      int* __restrict__ bcur, unsigned* __restrict__ binned) {
    __shared__ int hist[NBK];
    __shared__ int gbase[NBK];
    const int base = blockIdx.x * CHUNK;
    for (int i = threadIdx.x; i < NBK; i += 256) hist[i] = 0;
    __syncthreads();
    int myr[PERT], myc[PERT];
#pragma unroll
    for (int i = 0; i < PERT; ++i) {
        int idx = base + threadIdx.x + i * 256;
        if (idx < NE) {
            int r = r32[idx], c = c32[idx];
            myr[i] = r; myc[i] = c;
            atomicAdd(&hist[c >> 6], 1);
        } else {
            myc[i] = -1;
        }
    }
    __syncthreads();
    for (int b = threadIdx.x; b < NBK; b += 256) {
        int h = hist[b];
        gbase[b] = h ? atomicAdd(&bcur[b], h) : 0;
        hist[b] = 0;  // reuse as local cursor
    }
    __syncthreads();
#pragma unroll
    for (int i = 0; i < PERT; ++i) {
        int c = myc[i];
        if (c >= 0) {
            int bkt = c >> 6;
            int pos = gbase[bkt] + atomicAdd(&hist[bkt], 1);
            binned[pos] = (unsigned)myr[i] | ((unsigned)(c & 63) << 16);
        }
    }
}

// per-bucket sort: src[off[n] + i] = r, grouped per node (scatter span ~8KB/block)
__global__ void k_sort(const int* __restrict__ off, const unsigned* __restrict__ binned,
                       int* __restrict__ src) {
    __shared__ int soff[BSTEP];
    __shared__ int cur[BSTEP];
    const int b = blockIdx.x;
    const int nbase = b * BSTEP;
    if (threadIdx.x < BSTEP) {
        int n = nbase + threadIdx.x;
        soff[threadIdx.x] = (n <= NN) ? off[n] : 0;
        cur[threadIdx.x] = 0;
    }
    __syncthreads();
    const int p0 = off[nbase];
    const int p1 = off[min(nbase + BSTEP, NN)];
    for (int p = p0 + threadIdx.x; p < p1; p += 256) {
        unsigned rec = binned[p];
        int r = (int)(rec & 0xffffu);
        int cl = (int)(rec >> 16);
        int pos = soff[cl] + atomicAdd(&cur[cl], 1);
        src[pos] = r;
    }
}

// hs16[n*32+k] = bf16(dinv[n] * dot(x[n,:], W[:,k])) ; 20 lanes per node (64B rows)
__global__ void k_xw(const float* __restrict__ x, const float* __restrict__ W,
                     const int* __restrict__ cnt, __hip_bfloat16* __restrict__ hs16) {
    int t = blockIdx.x * blockDim.x + threadIdx.x;
    int n = t / EH;
    int k = t - n * EH;
    if (n >= NN) return;
    const float4* xr = (const float4*)(x + (size_t)n * FIN);
    float acc = 0.f;
#pragma unroll
    for (int j4 = 0; j4 < FIN / 4; ++j4) {
        float4 v = xr[j4];  // broadcast across the 20-lane group
        acc = fmaf(v.x, W[(4 * j4 + 0) * EH + k], acc);
        acc = fmaf(v.y, W[(4 * j4 + 1) * EH + k], acc);
        acc = fmaf(v.z, W[(4 * j4 + 2) * EH + k], acc);
        acc = fmaf(v.w, W[(4 * j4 + 3) * EH + k], acc);
    }
    float dinv = rsqrtf(1.0f + (float)cnt[n]);
    hs16[n * 32 + k] = __float2bfloat16(dinv * acc);
}

__device__ __forceinline__ float blo(unsigned u) { return __uint_as_float(u << 16); }
__device__ __forceinline__ float bhi(unsigned u) { return __uint_as_float(u & 0xffff0000u); }

// per-node gather + bias + relu; 20 lanes per node; 2-deep pipelined; zero atomics
__global__ void k_gather(const int* __restrict__ off, const int* __restrict__ src,
                         const int* __restrict__ cnt,
                         const __hip_bfloat16* __restrict__ hs16,
                         const float* __restrict__ bg, float* __restrict__ h1) {
    int t = blockIdx.x * blockDim.x + threadIdx.x;
    int n = t / EH;
    int k = t - n * EH;
    if (n >= NN) return;
    const unsigned short* hu = (const unsigned short*)hs16;
    float acc = blo((unsigned)hu[n * 32 + k]);  // self-loop term
    int e0 = off[n], e1 = off[n + 1];
    int e = e0;
    for (; e + 1 < e1; e += 2) {
        int r0 = src[e];       // broadcast across group
        int r1 = src[e + 1];
        float v0 = blo((unsigned)hu[r0 * 32 + k]);
        float v1 = blo((unsigned)hu[r1 * 32 + k]);
        acc += v0;
        acc += v1;
    }
    if (e < e1) acc += blo((unsigned)hu[src[e] * 32 + k]);
    float dinv = rsqrtf(1.0f + (float)cnt[n]);
    h1[(size_t)n * EH + k] = fmaxf(fmaf(dinv, acc, bg[k]), 0.f);
}

// A16[n,j] = bf16(h1[n,:] @ W1[0:20, j]);
// B16[n,j] = bf16(b1[j] + h1[nid,:] @ W1[40:60, j] + h1[n,:] @ W1[20:40, j])
__global__ void k_ab(const float* __restrict__ h1, const float* __restrict__ W1,
                     const float* __restrict__ b1, const void* nid_p,
                     __hip_bfloat16* __restrict__ A16, __hip_bfloat16* __restrict__ B16) {
    int t = blockIdx.x * blockDim.x + threadIdx.x;
    int n = t >> 6;
    int j = t & 63;
    if (n >= NN) return;
    int nid = *(const int*)nid_p;  // low 32 bits valid for int32 or int64 LE
    const float* hr = h1 + (size_t)n * EH;
    const float* hn = h1 + (size_t)nid * EH;  // broadcast
    float a = 0.f, b = b1[j];
#pragma unroll
    for (int k = 0; k < EH; ++k) {
        float hv = hr[k];
        a = fmaf(hv, W1[k * DH + j], a);
        b = fmaf(hv, W1[(EH + k) * DH + j], b);
        b = fmaf(hn[k], W1[(2 * EH + k) * DH + j], b);
    }
    A16[(size_t)n * DH + j] = __float2bfloat16(a);
    B16[(size_t)n * DH + j] = __float2bfloat16(b);
}

// per-edge decoder: 1 thread per edge, edge order (sequential eps/out).
__global__ void k_edge(const int* __restrict__ r32, const int* __restrict__ c32,
                       const __hip_bfloat16* __restrict__ A16,
                       const __hip_bfloat16* __restrict__ B16,
                       const float* __restrict__ W2, const float* __restrict__ b2,
                       const float* __restrict__ eps, float* __restrict__ out) {
    int e = blockIdx.x * blockDim.x + threadIdx.x;
    if (e >= NE) return;
    int r = r32[e], c = c32[e];
    const uint4* arow = (const uint4*)(A16 + (size_t)r * DH);
    const uint4* brow = (const uint4*)(B16 + (size_t)c * DH);
    float acc = 0.f;
#pragma unroll
    for (int j = 0; j < 8; ++j) {
        uint4 av = arow[j];
        uint4 bv = brow[j];
        acc = fmaf(fmaxf(blo(av.x) + blo(bv.x), 0.f), W2[8 * j + 0], acc);
        acc = fmaf(fmaxf(bhi(av.x) + bhi(bv.x), 0.f), W2[8 * j + 1], acc);
        acc = fmaf(fmaxf(blo(av.y) + blo(bv.y), 0.f), W2[8 * j + 2], acc);
        acc = fmaf(fmaxf(bhi(av.y) + bhi(bv.y), 0.f), W2[8 * j + 3], acc);
        acc = fmaf(fmaxf(blo(av.z) + blo(bv.z), 0.f), W2[8 * j + 4], acc);
        acc = fmaf(fmaxf(bhi(av.z) + bhi(bv.z), 0.f), W2[8 * j + 5], acc);
        acc = fmaf(fmaxf(blo(av.w) + blo(bv.w), 0.f), W2[8 * j + 6], acc);
        acc = fmaf(fmaxf(bhi(av.w) + bhi(bv.w), 0.f), W2[8 * j + 7], acc);
    }
    float ep = eps[e];
    // e = (bias-(1-bias))*eps + (1-bias), bias=1e-4
    float ee = fmaf(-0.9998f, ep, 0.9999f);
    float gate = logf(ee) - log1pf(-ee) + acc + b2[0];
    out[e] = 1.0f / (1.0f + expf(-gate));
}

// ---------------- launch ----------------

extern "C" void kernel_launch(void* const* d_in, const int* in_sizes, int n_in,
                              void* d_out, int out_size, void* d_ws, size_t ws_size,
                              hipStream_t stream) {
    const float* x   = (const float*)d_in[0];
    const void*  ei  = d_in[1];
    const void*  nid = d_in[2];
    const float* eps = (const float*)d_in[3];
    const float* Wg  = (const float*)d_in[4];
    const float* bg  = (const float*)d_in[5];
    const float* W1  = (const float*)d_in[6];
    const float* b1  = (const float*)d_in[7];
    const float* W2  = (const float*)d_in[8];
    const float* b2  = (const float*)d_in[9];
    float* out = (float*)d_out;

    float* ws = (float*)d_ws;
    // Total ~11.6M floats ≈ 46.3 MB (proven footprint in R1).
    int*  r32    = (int*)(ws + 0);                            // 1.6M
    int*  c32    = (int*)(ws + 1600000);                      // 1.6M
    unsigned* binned = (unsigned*)(ws + 3200000);             // 1.6M
    int*  src    = (int*)(ws + 4800000);                      // 1.6M
    __hip_bfloat16* hs16 = (__hip_bfloat16*)(ws + 6400000);   // 0.8M floats
    float* h1    = ws + 7200000;                              // 1.0M
    __hip_bfloat16* A16 = (__hip_bfloat16*)(ws + 8200000);    // 1.6M floats
    __hip_bfloat16* B16 = (__hip_bfloat16*)(ws + 9800000);    // 1.6M floats
    int* cnt     = (int*)(ws + 11400000);
    int* off     = (int*)(ws + 11460000);
    int* bcur    = (int*)(ws + 11520000);
    int* flag    = (int*)(ws + 11530000);

    dim3 blk(256);
    k_init<<<(NN + 255) / 256, blk, 0, stream>>>(cnt, flag, ei);
    k_cvt<<<(NE + 255) / 256, blk, 0, stream>>>(ei, flag, r32, c32, cnt);
    k_scan<<<1, 1024, 0, stream>>>(cnt, off, bcur);
    k_bin<<<(NE + CHUNK - 1) / CHUNK, blk, 0, stream>>>(r32, c32, bcur, binned);
    k_sort<<<NBK, blk, 0, stream>>>(off, binned, src);
    k_xw<<<(NN * EH + 255) / 256, blk, 0, stream>>>(x, Wg, cnt, hs16);
    k_gather<<<(NN * EH + 255) / 256, blk, 0, stream>>>(off, src, cnt, hs16, bg, h1);
    k_ab<<<(NN * 64 + 255) / 256, blk, 0, stream>>>(h1, W1, b1, nid, A16, B16);
    k_edge<<<(NE + 255) / 256, blk, 0, stream>>>(r32, c32, A16, B16, W2, b2, eps, out);
}

// Round 8
// 295.779 us; speedup vs baseline: 1.8866x; 1.2848x over previous
//
#include <hip/hip_runtime.h>
#include <hip/hip_bf16.h>
#include <math.h>

#define NN 50000
#define NE 1600000
#define FIN 128
#define EH 20
#define DH 64

#define BSTEP 64                        // nodes per bucket
#define NBK ((NN + BSTEP - 1) / BSTEP)  // 782 buckets
#define CHUNK 4096                      // edges per k_bin block
#define PERT (CHUNK / 256)              // 16 edges per thread
#define NBLK ((NN + 255) / 256)         // 196 scan blocks

// ---------------- kernels ----------------

// zero cnt and detect edge_index width (int64 vs int32)
__global__ void k_init(int* cnt, int* flag, const void* ei) {
    int i = blockIdx.x * blockDim.x + threadIdx.x;
    if (i < NN) cnt[i] = 0;
    if (i == 0) {
        const int* w = (const int*)ei;
        int all0 = 1;
        for (int j = 1; j < 128; j += 2) all0 &= (w[j] == 0);
        *flag = all0;  // 1 => int64 layout (high words zero), 0 => int32
    }
}

// convert edge_index to int32 r/c arrays and count in-degree of col
__global__ void k_cvt(const void* ei, const int* flag, int* r32, int* c32, int* cnt) {
    int e = blockIdx.x * blockDim.x + threadIdx.x;
    if (e >= NE) return;
    int r, c;
    if (*flag) {
        const long long* p = (const long long*)ei;
        r = (int)p[e];
        c = (int)p[NE + e];
    } else {
        const int* p = (const int*)ei;
        r = p[e];
        c = p[NE + e];
    }
    r32[e] = r;
    c32[e] = c;
    atomicAdd(&cnt[c], 1);
}

// hierarchical scan, level A: per-block sum of 256 cnt values
__global__ void k_scanA(const int* __restrict__ cnt, int* __restrict__ bsum) {
    __shared__ int red[256];
    int idx = blockIdx.x * 256 + threadIdx.x;
    red[threadIdx.x] = (idx < NN) ? cnt[idx] : 0;
    __syncthreads();
    for (int d = 128; d > 0; d >>= 1) {
        if (threadIdx.x < d) red[threadIdx.x] += red[threadIdx.x + d];
        __syncthreads();
    }
    if (threadIdx.x == 0) bsum[blockIdx.x] = red[0];
}

// level B: single small block scans the 196 block sums (exclusive)
__global__ void k_scanB(const int* __restrict__ bsum, int* __restrict__ bpre,
                        int* __restrict__ off) {
    __shared__ int s[256];
    int t = threadIdx.x;
    int v = (t < NBLK) ? bsum[t] : 0;
    s[t] = v;
    __syncthreads();
    for (int d = 1; d < 256; d <<= 1) {
        int u = (t >= d) ? s[t - d] : 0;
        __syncthreads();
        s[t] += u;
        __syncthreads();
    }
    if (t < NBLK) bpre[t] = s[t] - v;  // exclusive prefix
    if (t == 0) off[NN] = NE;
}

// level C: per-block exclusive scan + block prefix -> off; also bucket cursors
__global__ void k_scanC(const int* __restrict__ cnt, const int* __restrict__ bpre,
                        int* __restrict__ off, int* __restrict__ bcur) {
    __shared__ int s[256];
    int t = threadIdx.x;
    int idx = blockIdx.x * 256 + t;
    int v = (idx < NN) ? cnt[idx] : 0;
    s[t] = v;
    __syncthreads();
    for (int d = 1; d < 256; d <<= 1) {
        int u = (t >= d) ? s[t - d] : 0;
        __syncthreads();
        s[t] += u;
        __syncthreads();
    }
    if (idx < NN) {
        int o = bpre[blockIdx.x] + s[t] - v;  // exclusive
        off[idx] = o;
        if ((idx & 63) == 0) bcur[idx >> 6] = o;
    }
}

// two-level binned fill: packed records (r | c_local<<16) grouped by bucket.
__global__ void k_bin(const int* __restrict__ r32, const int* __restrict__ c32,
                      int* __restrict__ bcur, unsigned* __restrict__ binned) {
    __shared__ int hist[NBK];
    __shared__ int gbase[NBK];
    const int base = blockIdx.x * CHUNK;
    for (int i = threadIdx.x; i < NBK; i += 256) hist[i] = 0;
    __syncthreads();
    int myr[PERT], myc[PERT];
#pragma unroll
    for (int i = 0; i < PERT; ++i) {
        int idx = base + threadIdx.x + i * 256;
        if (idx < NE) {
            int r = r32[idx], c = c32[idx];
            myr[i] = r; myc[i] = c;
            atomicAdd(&hist[c >> 6], 1);
        } else {
            myc[i] = -1;
        }
    }
    __syncthreads();
    for (int b = threadIdx.x; b < NBK; b += 256) {
        int h = hist[b];
        gbase[b] = h ? atomicAdd(&bcur[b], h) : 0;
        hist[b] = 0;  // reuse as local cursor
    }
    __syncthreads();
#pragma unroll
    for (int i = 0; i < PERT; ++i) {
        int c = myc[i];
        if (c >= 0) {
            int bkt = c >> 6;
            int pos = gbase[bkt] + atomicAdd(&hist[bkt], 1);
            binned[pos] = (unsigned)myr[i] | ((unsigned)(c & 63) << 16);
        }
    }
}

// per-bucket sort: src[off[n] + i] = r, grouped per node (scatter span ~8KB/block)
__global__ void k_sort(const int* __restrict__ off, const unsigned* __restrict__ binned,
                       int* __restrict__ src) {
    __shared__ int soff[BSTEP];
    __shared__ int cur[BSTEP];
    const int b = blockIdx.x;
    const int nbase = b * BSTEP;
    if (threadIdx.x < BSTEP) {
        int n = nbase + threadIdx.x;
        soff[threadIdx.x] = (n <= NN) ? off[n] : 0;
        cur[threadIdx.x] = 0;
    }
    __syncthreads();
    const int p0 = off[nbase];
    const int p1 = off[min(nbase + BSTEP, NN)];
    for (int p = p0 + threadIdx.x; p < p1; p += 256) {
        unsigned rec = binned[p];
        int r = (int)(rec & 0xffffu);
        int cl = (int)(rec >> 16);
        int pos = soff[cl] + atomicAdd(&cur[cl], 1);
        src[pos] = r;
    }
}

// hs16[n*32+k] = bf16(dinv[n] * dot(x[n,:], W[:,k])) ; 20 lanes per node (64B rows)
__global__ void k_xw(const float* __restrict__ x, const float* __restrict__ W,
                     const int* __restrict__ cnt, __hip_bfloat16* __restrict__ hs16) {
    int t = blockIdx.x * blockDim.x + threadIdx.x;
    int n = t / EH;
    int k = t - n * EH;
    if (n >= NN) return;
    const float4* xr = (const float4*)(x + (size_t)n * FIN);
    float acc = 0.f;
#pragma unroll
    for (int j4 = 0; j4 < FIN / 4; ++j4) {
        float4 v = xr[j4];  // broadcast across the 20-lane group
        acc = fmaf(v.x, W[(4 * j4 + 0) * EH + k], acc);
        acc = fmaf(v.y, W[(4 * j4 + 1) * EH + k], acc);
        acc = fmaf(v.z, W[(4 * j4 + 2) * EH + k], acc);
        acc = fmaf(v.w, W[(4 * j4 + 3) * EH + k], acc);
    }
    float dinv = rsqrtf(1.0f + (float)cnt[n]);
    hs16[n * 32 + k] = __float2bfloat16(dinv * acc);
}

__device__ __forceinline__ float blo(unsigned u) { return __uint_as_float(u << 16); }
__device__ __forceinline__ float bhi(unsigned u) { return __uint_as_float(u & 0xffff0000u); }

// per-node gather + bias + relu; 20 lanes per node; 2-deep pipelined; zero atomics
__global__ void k_gather(const int* __restrict__ off, const int* __restrict__ src,
                         const int* __restrict__ cnt,
                         const __hip_bfloat16* __restrict__ hs16,
                         const float* __restrict__ bg, float* __restrict__ h1) {
    int t = blockIdx.x * blockDim.x + threadIdx.x;
    int n = t / EH;
    int k = t - n * EH;
    if (n >= NN) return;
    const unsigned short* hu = (const unsigned short*)hs16;
    float acc = blo((unsigned)hu[n * 32 + k]);  // self-loop term
    int e0 = off[n], e1 = off[n + 1];
    int e = e0;
    for (; e + 1 < e1; e += 2) {
        int r0 = src[e];       // broadcast across group
        int r1 = src[e + 1];
        float v0 = blo((unsigned)hu[r0 * 32 + k]);
        float v1 = blo((unsigned)hu[r1 * 32 + k]);
        acc += v0;
        acc += v1;
    }
    if (e < e1) acc += blo((unsigned)hu[src[e] * 32 + k]);
    float dinv = rsqrtf(1.0f + (float)cnt[n]);
    h1[(size_t)n * EH + k] = fmaxf(fmaf(dinv, acc, bg[k]), 0.f);
}

// A16[n,j] = bf16(h1[n,:] @ W1[0:20, j]);
// B16[n,j] = bf16(b1[j] + h1[nid,:] @ W1[40:60, j] + h1[n,:] @ W1[20:40, j])
__global__ void k_ab(const float* __restrict__ h1, const float* __restrict__ W1,
                     const float* __restrict__ b1, const void* nid_p,
                     __hip_bfloat16* __restrict__ A16, __hip_bfloat16* __restrict__ B16) {
    int t = blockIdx.x * blockDim.x + threadIdx.x;
    int n = t >> 6;
    int j = t & 63;
    if (n >= NN) return;
    int nid = *(const int*)nid_p;  // low 32 bits valid for int32 or int64 LE
    const float* hr = h1 + (size_t)n * EH;
    const float* hn = h1 + (size_t)nid * EH;  // broadcast
    float a = 0.f, b = b1[j];
#pragma unroll
    for (int k = 0; k < EH; ++k) {
        float hv = hr[k];
        a = fmaf(hv, W1[k * DH + j], a);
        b = fmaf(hv, W1[(EH + k) * DH + j], b);
        b = fmaf(hn[k], W1[(2 * EH + k) * DH + j], b);
    }
    A16[(size_t)n * DH + j] = __float2bfloat16(a);
    B16[(size_t)n * DH + j] = __float2bfloat16(b);
}

// per-edge decoder: 1 thread per edge, edge order (sequential eps/out).
__global__ void k_edge(const int* __restrict__ r32, const int* __restrict__ c32,
                       const __hip_bfloat16* __restrict__ A16,
                       const __hip_bfloat16* __restrict__ B16,
                       const float* __restrict__ W2, const float* __restrict__ b2,
                       const float* __restrict__ eps, float* __restrict__ out) {
    int e = blockIdx.x * blockDim.x + threadIdx.x;
    if (e >= NE) return;
    int r = r32[e], c = c32[e];
    const uint4* arow = (const uint4*)(A16 + (size_t)r * DH);
    const uint4* brow = (const uint4*)(B16 + (size_t)c * DH);
    float acc = 0.f;
#pragma unroll
    for (int j = 0; j < 8; ++j) {
        uint4 av = arow[j];
        uint4 bv = brow[j];
        acc = fmaf(fmaxf(blo(av.x) + blo(bv.x), 0.f), W2[8 * j + 0], acc);
        acc = fmaf(fmaxf(bhi(av.x) + bhi(bv.x), 0.f), W2[8 * j + 1], acc);
        acc = fmaf(fmaxf(blo(av.y) + blo(bv.y), 0.f), W2[8 * j + 2], acc);
        acc = fmaf(fmaxf(bhi(av.y) + bhi(bv.y), 0.f), W2[8 * j + 3], acc);
        acc = fmaf(fmaxf(blo(av.z) + blo(bv.z), 0.f), W2[8 * j + 4], acc);
        acc = fmaf(fmaxf(bhi(av.z) + bhi(bv.z), 0.f), W2[8 * j + 5], acc);
        acc = fmaf(fmaxf(blo(av.w) + blo(bv.w), 0.f), W2[8 * j + 6], acc);
        acc = fmaf(fmaxf(bhi(av.w) + bhi(bv.w), 0.f), W2[8 * j + 7], acc);
    }
    float ep = eps[e];
    // e = (bias-(1-bias))*eps + (1-bias), bias=1e-4
    float ee = fmaf(-0.9998f, ep, 0.9999f);
    float gate = logf(ee) - log1pf(-ee) + acc + b2[0];
    out[e] = 1.0f / (1.0f + expf(-gate));
}

// ---------------- launch ----------------

extern "C" void kernel_launch(void* const* d_in, const int* in_sizes, int n_in,
                              void* d_out, int out_size, void* d_ws, size_t ws_size,
                              hipStream_t stream) {
    const float* x   = (const float*)d_in[0];
    const void*  ei  = d_in[1];
    const void*  nid = d_in[2];
    const float* eps = (const float*)d_in[3];
    const float* Wg  = (const float*)d_in[4];
    const float* bg  = (const float*)d_in[5];
    const float* W1  = (const float*)d_in[6];
    const float* b1  = (const float*)d_in[7];
    const float* W2  = (const float*)d_in[8];
    const float* b2  = (const float*)d_in[9];
    float* out = (float*)d_out;

    float* ws = (float*)d_ws;
    // Total ~11.6M floats ≈ 46.3 MB (proven footprint in R1).
    int*  r32    = (int*)(ws + 0);                            // 1.6M
    int*  c32    = (int*)(ws + 1600000);                      // 1.6M
    unsigned* binned = (unsigned*)(ws + 3200000);             // 1.6M
    int*  src    = (int*)(ws + 4800000);                      // 1.6M
    __hip_bfloat16* hs16 = (__hip_bfloat16*)(ws + 6400000);   // 0.8M floats
    float* h1    = ws + 7200000;                              // 1.0M
    __hip_bfloat16* A16 = (__hip_bfloat16*)(ws + 8200000);    // 1.6M floats
    __hip_bfloat16* B16 = (__hip_bfloat16*)(ws + 9800000);    // 1.6M floats
    int* cnt     = (int*)(ws + 11400000);
    int* off     = (int*)(ws + 11460000);
    int* bcur    = (int*)(ws + 11520000);
    int* bsum    = (int*)(ws + 11524000);
    int* bpre    = (int*)(ws + 11525000);
    int* flag    = (int*)(ws + 11526000);

    dim3 blk(256);
    k_init<<<(NN + 255) / 256, blk, 0, stream>>>(cnt, flag, ei);
    k_cvt<<<(NE + 255) / 256, blk, 0, stream>>>(ei, flag, r32, c32, cnt);
    k_scanA<<<NBLK, blk, 0, stream>>>(cnt, bsum);
    k_scanB<<<1, blk, 0, stream>>>(bsum, bpre, off);
    k_scanC<<<NBLK, blk, 0, stream>>>(cnt, bpre, off, bcur);
    k_bin<<<(NE + CHUNK - 1) / CHUNK, blk, 0, stream>>>(r32, c32, bcur, binned);
    k_sort<<<NBK, blk, 0, stream>>>(off, binned, src);
    k_xw<<<(NN * EH + 255) / 256, blk, 0, stream>>>(x, Wg, cnt, hs16);
    k_gather<<<(NN * EH + 255) / 256, blk, 0, stream>>>(off, src, cnt, hs16, bg, h1);
    k_ab<<<(NN * 64 + 255) / 256, blk, 0, stream>>>(h1, W1, b1, nid, A16, B16);
    k_edge<<<(NE + 255) / 256, blk, 0, stream>>>(r32, c32, A16, B16, W2, b2, eps, out);
}

// Round 9
// 264.216 us; speedup vs baseline: 2.1119x; 1.1195x over previous
//
#include <hip/hip_runtime.h>
#include <hip/hip_bf16.h>
#include <math.h>

#define NN 50000
#define NE 1600000
#define FIN 128
#define EH 20
#define DH 64

#define BSTEP 64                        // nodes per bucket
#define NBK ((NN + BSTEP - 1) / BSTEP)  // 782 buckets
#define CHUNK 4096                      // edges per k_bin block
#define PERT (CHUNK / 256)              // 16 edges per thread
#define NBLK ((NN + 255) / 256)         // 196 scan blocks

// ---------------- kernels ----------------

// zero cnt and detect edge_index width (int64 vs int32)
__global__ void k_init(int* cnt, int* flag, const void* ei) {
    int i = blockIdx.x * blockDim.x + threadIdx.x;
    if (i < NN) cnt[i] = 0;
    if (i == 0) {
        const int* w = (const int*)ei;
        int all0 = 1;
        for (int j = 1; j < 128; j += 2) all0 &= (w[j] == 0);
        *flag = all0;  // 1 => int64 layout (high words zero), 0 => int32
    }
}

// convert edge_index to int32 r/c arrays and count in-degree of col
__global__ void k_cvt(const void* ei, const int* flag, int* r32, int* c32, int* cnt) {
    int e = blockIdx.x * blockDim.x + threadIdx.x;
    if (e >= NE) return;
    int r, c;
    if (*flag) {
        const long long* p = (const long long*)ei;
        r = (int)p[e];
        c = (int)p[NE + e];
    } else {
        const int* p = (const int*)ei;
        r = p[e];
        c = p[NE + e];
    }
    r32[e] = r;
    c32[e] = c;
    atomicAdd(&cnt[c], 1);
}

// hierarchical scan, level A: per-block sum of 256 cnt values
__global__ void k_scanA(const int* __restrict__ cnt, int* __restrict__ bsum) {
    __shared__ int red[256];
    int idx = blockIdx.x * 256 + threadIdx.x;
    red[threadIdx.x] = (idx < NN) ? cnt[idx] : 0;
    __syncthreads();
    for (int d = 128; d > 0; d >>= 1) {
        if (threadIdx.x < d) red[threadIdx.x] += red[threadIdx.x + d];
        __syncthreads();
    }
    if (threadIdx.x == 0) bsum[blockIdx.x] = red[0];
}

// level B: single small block scans the 196 block sums (exclusive)
__global__ void k_scanB(const int* __restrict__ bsum, int* __restrict__ bpre,
                        int* __restrict__ off) {
    __shared__ int s[256];
    int t = threadIdx.x;
    int v = (t < NBLK) ? bsum[t] : 0;
    s[t] = v;
    __syncthreads();
    for (int d = 1; d < 256; d <<= 1) {
        int u = (t >= d) ? s[t - d] : 0;
        __syncthreads();
        s[t] += u;
        __syncthreads();
    }
    if (t < NBLK) bpre[t] = s[t] - v;  // exclusive prefix
    if (t == 0) off[NN] = NE;
}

// level C: per-block exclusive scan + block prefix -> off; also bucket cursors
__global__ void k_scanC(const int* __restrict__ cnt, const int* __restrict__ bpre,
                        int* __restrict__ off, int* __restrict__ bcur) {
    __shared__ int s[256];
    int t = threadIdx.x;
    int idx = blockIdx.x * 256 + t;
    int v = (idx < NN) ? cnt[idx] : 0;
    s[t] = v;
    __syncthreads();
    for (int d = 1; d < 256; d <<= 1) {
        int u = (t >= d) ? s[t - d] : 0;
        __syncthreads();
        s[t] += u;
        __syncthreads();
    }
    if (idx < NN) {
        int o = bpre[blockIdx.x] + s[t] - v;  // exclusive
        off[idx] = o;
        if ((idx & 63) == 0) bcur[idx >> 6] = o;
    }
}

// two-level binned fill: packed records (r | c_local<<16) grouped by bucket.
__global__ void k_bin(const int* __restrict__ r32, const int* __restrict__ c32,
                      int* __restrict__ bcur, unsigned* __restrict__ binned) {
    __shared__ int hist[NBK];
    __shared__ int gbase[NBK];
    const int base = blockIdx.x * CHUNK;
    for (int i = threadIdx.x; i < NBK; i += 256) hist[i] = 0;
    __syncthreads();
    int myr[PERT], myc[PERT];
#pragma unroll
    for (int i = 0; i < PERT; ++i) {
        int idx = base + threadIdx.x + i * 256;
        if (idx < NE) {
            int r = r32[idx], c = c32[idx];
            myr[i] = r; myc[i] = c;
            atomicAdd(&hist[c >> 6], 1);
        } else {
            myc[i] = -1;
        }
    }
    __syncthreads();
    for (int b = threadIdx.x; b < NBK; b += 256) {
        int h = hist[b];
        gbase[b] = h ? atomicAdd(&bcur[b], h) : 0;
        hist[b] = 0;  // reuse as local cursor
    }
    __syncthreads();
#pragma unroll
    for (int i = 0; i < PERT; ++i) {
        int c = myc[i];
        if (c >= 0) {
            int bkt = c >> 6;
            int pos = gbase[bkt] + atomicAdd(&hist[bkt], 1);
            binned[pos] = (unsigned)myr[i] | ((unsigned)(c & 63) << 16);
        }
    }
}

// per-bucket sort: src[off[n] + i] = r, grouped per node (scatter span ~8KB/block)
__global__ void k_sort(const int* __restrict__ off, const unsigned* __restrict__ binned,
                       int* __restrict__ src) {
    __shared__ int soff[BSTEP];
    __shared__ int cur[BSTEP];
    const int b = blockIdx.x;
    const int nbase = b * BSTEP;
    if (threadIdx.x < BSTEP) {
        int n = nbase + threadIdx.x;
        soff[threadIdx.x] = (n <= NN) ? off[n] : 0;
        cur[threadIdx.x] = 0;
    }
    __syncthreads();
    const int p0 = off[nbase];
    const int p1 = off[min(nbase + BSTEP, NN)];
    for (int p = p0 + threadIdx.x; p < p1; p += 256) {
        unsigned rec = binned[p];
        int r = (int)(rec & 0xffffu);
        int cl = (int)(rec >> 16);
        int pos = soff[cl] + atomicAdd(&cur[cl], 1);
        src[pos] = r;
    }
}

// hs16[n*32+k] = bf16(dinv[n] * dot(x[n,:], W[:,k])) ; 20 lanes per node (64B rows)
__global__ void k_xw(const float* __restrict__ x, const float* __restrict__ W,
                     const int* __restrict__ cnt, __hip_bfloat16* __restrict__ hs16) {
    int t = blockIdx.x * blockDim.x + threadIdx.x;
    int n = t / EH;
    int k = t - n * EH;
    if (n >= NN) return;
    const float4* xr = (const float4*)(x + (size_t)n * FIN);
    float acc = 0.f;
#pragma unroll
    for (int j4 = 0; j4 < FIN / 4; ++j4) {
        float4 v = xr[j4];  // broadcast across the 20-lane group
        acc = fmaf(v.x, W[(4 * j4 + 0) * EH + k], acc);
        acc = fmaf(v.y, W[(4 * j4 + 1) * EH + k], acc);
        acc = fmaf(v.z, W[(4 * j4 + 2) * EH + k], acc);
        acc = fmaf(v.w, W[(4 * j4 + 3) * EH + k], acc);
    }
    float dinv = rsqrtf(1.0f + (float)cnt[n]);
    hs16[n * 32 + k] = __float2bfloat16(dinv * acc);
}

__device__ __forceinline__ float blo(unsigned u) { return __uint_as_float(u << 16); }
__device__ __forceinline__ float bhi(unsigned u) { return __uint_as_float(u & 0xffff0000u); }

// per-node gather + bias + relu; 10 lanes per node, each lane owns 2 feature slots
// (one packed 4B load per edge per lane); zero atomics
__global__ void k_gather(const int* __restrict__ off, const int* __restrict__ src,
                         const int* __restrict__ cnt,
                         const __hip_bfloat16* __restrict__ hs16,
                         const float* __restrict__ bg, float* __restrict__ h1) {
    int t = blockIdx.x * blockDim.x + threadIdx.x;
    int n = t / 10;
    int kk = t - n * 10;     // feature pair index: handles k=2kk, 2kk+1
    if (n >= NN) return;
    const unsigned* hu = (const unsigned*)hs16;  // row stride 16 uints (32 bf16)
    unsigned self = hu[n * 16 + kk];
    float acc0 = blo(self), acc1 = bhi(self);
    int e0 = off[n], e1 = off[n + 1];
    int e = e0;
    for (; e + 1 < e1; e += 2) {
        int r0 = src[e];       // broadcast across group
        int r1 = src[e + 1];
        unsigned v0 = hu[r0 * 16 + kk];
        unsigned v1 = hu[r1 * 16 + kk];
        acc0 += blo(v0); acc1 += bhi(v0);
        acc0 += blo(v1); acc1 += bhi(v1);
    }
    if (e < e1) {
        unsigned v = hu[src[e] * 16 + kk];
        acc0 += blo(v); acc1 += bhi(v);
    }
    float dinv = rsqrtf(1.0f + (float)cnt[n]);
    float2 res;
    res.x = fmaxf(fmaf(dinv, acc0, bg[2 * kk]), 0.f);
    res.y = fmaxf(fmaf(dinv, acc1, bg[2 * kk + 1]), 0.f);
    *(float2*)(h1 + (size_t)n * EH + 2 * kk) = res;
}

// A16[n,j] = bf16(h1[n,:] @ W1[0:20, j]);
// B16[n,j] = bf16(b1[j] + h1[nid,:] @ W1[40:60, j] + h1[n,:] @ W1[20:40, j])
__global__ void k_ab(const float* __restrict__ h1, const float* __restrict__ W1,
                     const float* __restrict__ b1, const void* nid_p,
                     __hip_bfloat16* __restrict__ A16, __hip_bfloat16* __restrict__ B16) {
    int t = blockIdx.x * blockDim.x + threadIdx.x;
    int n = t >> 6;
    int j = t & 63;
    if (n >= NN) return;
    int nid = *(const int*)nid_p;  // low 32 bits valid for int32 or int64 LE
    const float* hr = h1 + (size_t)n * EH;
    const float* hn = h1 + (size_t)nid * EH;  // broadcast
    float a = 0.f, b = b1[j];
#pragma unroll
    for (int k = 0; k < EH; ++k) {
        float hv = hr[k];
        a = fmaf(hv, W1[k * DH + j], a);
        b = fmaf(hv, W1[(EH + k) * DH + j], b);
        b = fmaf(hn[k], W1[(2 * EH + k) * DH + j], b);
    }
    A16[(size_t)n * DH + j] = __float2bfloat16(a);
    B16[(size_t)n * DH + j] = __float2bfloat16(b);
}

// per-edge decoder: 2 lanes per edge, each lane handles one 64B half of the rows.
__global__ void k_edge(const int* __restrict__ r32, const int* __restrict__ c32,
                       const __hip_bfloat16* __restrict__ A16,
                       const __hip_bfloat16* __restrict__ B16,
                       const float* __restrict__ W2, const float* __restrict__ b2,
                       const float* __restrict__ eps, float* __restrict__ out) {
    int t = blockIdx.x * blockDim.x + threadIdx.x;
    int e = t >> 1;
    if (e >= NE) return;
    int half = t & 1;
    int r = r32[e], c = c32[e];
    const uint4* arow = (const uint4*)(A16 + (size_t)r * DH) + half * 4;
    const uint4* brow = (const uint4*)(B16 + (size_t)c * DH) + half * 4;
    const float* w = W2 + half * 32;
    float acc = 0.f;
#pragma unroll
    for (int j = 0; j < 4; ++j) {
        uint4 av = arow[j];
        uint4 bv = brow[j];
        acc = fmaf(fmaxf(blo(av.x) + blo(bv.x), 0.f), w[8 * j + 0], acc);
        acc = fmaf(fmaxf(bhi(av.x) + bhi(bv.x), 0.f), w[8 * j + 1], acc);
        acc = fmaf(fmaxf(blo(av.y) + blo(bv.y), 0.f), w[8 * j + 2], acc);
        acc = fmaf(fmaxf(bhi(av.y) + bhi(bv.y), 0.f), w[8 * j + 3], acc);
        acc = fmaf(fmaxf(blo(av.z) + blo(bv.z), 0.f), w[8 * j + 4], acc);
        acc = fmaf(fmaxf(bhi(av.z) + bhi(bv.z), 0.f), w[8 * j + 5], acc);
        acc = fmaf(fmaxf(blo(av.w) + blo(bv.w), 0.f), w[8 * j + 6], acc);
        acc = fmaf(fmaxf(bhi(av.w) + bhi(bv.w), 0.f), w[8 * j + 7], acc);
    }
    acc += __shfl_xor(acc, 1);
    if (half == 0) {
        float ep = eps[e];
        // e = (bias-(1-bias))*eps + (1-bias), bias=1e-4
        float ee = fmaf(-0.9998f, ep, 0.9999f);
        float gate = logf(ee) - log1pf(-ee) + acc + b2[0];
        out[e] = 1.0f / (1.0f + expf(-gate));
    }
}

// ---------------- launch ----------------

extern "C" void kernel_launch(void* const* d_in, const int* in_sizes, int n_in,
                              void* d_out, int out_size, void* d_ws, size_t ws_size,
                              hipStream_t stream) {
    const float* x   = (const float*)d_in[0];
    const void*  ei  = d_in[1];
    const void*  nid = d_in[2];
    const float* eps = (const float*)d_in[3];
    const float* Wg  = (const float*)d_in[4];
    const float* bg  = (const float*)d_in[5];
    const float* W1  = (const float*)d_in[6];
    const float* b1  = (const float*)d_in[7];
    const float* W2  = (const float*)d_in[8];
    const float* b2  = (const float*)d_in[9];
    float* out = (float*)d_out;

    float* ws = (float*)d_ws;
    // Total ~11.6M floats ≈ 46.3 MB (proven footprint in R1).
    int*  r32    = (int*)(ws + 0);                            // 1.6M
    int*  c32    = (int*)(ws + 1600000);                      // 1.6M
    unsigned* binned = (unsigned*)(ws + 3200000);             // 1.6M
    int*  src    = (int*)(ws + 4800000);                      // 1.6M
    __hip_bfloat16* hs16 = (__hip_bfloat16*)(ws + 6400000);   // 0.8M floats
    float* h1    = ws + 7200000;                              // 1.0M
    __hip_bfloat16* A16 = (__hip_bfloat16*)(ws + 8200000);    // 1.6M floats
    __hip_bfloat16* B16 = (__hip_bfloat16*)(ws + 9800000);    // 1.6M floats
    int* cnt     = (int*)(ws + 11400000);
    int* off     = (int*)(ws + 11460000);
    int* bcur    = (int*)(ws + 11520000);
    int* bsum    = (int*)(ws + 11524000);
    int* bpre    = (int*)(ws + 11525000);
    int* flag    = (int*)(ws + 11526000);

    dim3 blk(256);
    k_init<<<(NN + 255) / 256, blk, 0, stream>>>(cnt, flag, ei);
    k_cvt<<<(NE + 255) / 256, blk, 0, stream>>>(ei, flag, r32, c32, cnt);
    k_scanA<<<NBLK, blk, 0, stream>>>(cnt, bsum);
    k_scanB<<<1, blk, 0, stream>>>(bsum, bpre, off);
    k_scanC<<<NBLK, blk, 0, stream>>>(cnt, bpre, off, bcur);
    k_bin<<<(NE + CHUNK - 1) / CHUNK, blk, 0, stream>>>(r32, c32, bcur, binned);
    k_sort<<<NBK, blk, 0, stream>>>(off, binned, src);
    k_xw<<<(NN * EH + 255) / 256, blk, 0, stream>>>(x, Wg, cnt, hs16);
    k_gather<<<(NN * 10 + 255) / 256, blk, 0, stream>>>(off, src, cnt, hs16, bg, h1);
    k_ab<<<(NN * 64 + 255) / 256, blk, 0, stream>>>(h1, W1, b1, nid, A16, B16);
    k_edge<<<((size_t)NE * 2 + 255) / 256, blk, 0, stream>>>(r32, c32, A16, B16, W2, b2, eps, out);
}

// Round 10
// 209.650 us; speedup vs baseline: 2.6616x; 1.2603x over previous
//
#include <hip/hip_runtime.h>
#include <hip/hip_bf16.h>
#include <math.h>

#define NN 50000
#define NE 1600000
#define FIN 128
#define EH 20
#define DH 64

#define BSTEP 64                        // nodes per bucket
#define NBK ((NN + BSTEP - 1) / BSTEP)  // 782 buckets
#define CHUNK 4096                      // edges per counting/binning block
#define PERT (CHUNK / 256)              // 16 edges per thread

// ---------------- kernels ----------------

// zero bucket counters and detect edge_index width (int64 vs int32)
__global__ void k_init(int* bcnt, int* flag, const void* ei) {
    int i = threadIdx.x;
    for (int b = i; b < NBK; b += 1024) bcnt[b] = 0;
    if (i == 0) {
        const int* w = (const int*)ei;
        int all0 = 1;
        for (int j = 1; j < 128; j += 2) all0 &= (w[j] == 0);
        *flag = all0;  // 1 => int64 layout (high words zero), 0 => int32
    }
}

__device__ __forceinline__ int ld_col(const void* ei, int w64, size_t idx) {
    return w64 ? (int)((const long long*)ei)[idx] : ((const int*)ei)[idx];
}

// count edges per 64-node bucket (LDS histogram, few global atomics)
__global__ void k_cnt(const void* ei, const int* flag, int* bcnt) {
    __shared__ int hist[NBK];
    for (int i = threadIdx.x; i < NBK; i += 256) hist[i] = 0;
    __syncthreads();
    const int base = blockIdx.x * CHUNK;
    const int w64 = *flag;
#pragma unroll
    for (int i = 0; i < PERT; ++i) {
        int idx = base + threadIdx.x + i * 256;
        if (idx < NE) {
            int c = ld_col(ei, w64, (size_t)NE + idx);
            atomicAdd(&hist[c >> 6], 1);
        }
    }
    __syncthreads();
    for (int b = threadIdx.x; b < NBK; b += 256)
        if (hist[b]) atomicAdd(&bcnt[b], hist[b]);
}

// single-block exclusive scan of bucket counts -> boff, bcur
__global__ void k_bscan(const int* __restrict__ bcnt, int* __restrict__ boff,
                        int* __restrict__ bcur, int* __restrict__ off) {
    __shared__ int s[1024];
    int t = threadIdx.x;
    int v = (t < NBK) ? bcnt[t] : 0;
    s[t] = v;
    __syncthreads();
    for (int d = 1; d < 1024; d <<= 1) {
        int u = (t >= d) ? s[t - d] : 0;
        __syncthreads();
        s[t] += u;
        __syncthreads();
    }
    if (t < NBK) {
        int e = s[t] - v;  // exclusive prefix
        boff[t] = e;
        bcur[t] = e;
    }
    if (t == 0) { boff[NBK] = NE; off[NN] = NE; }
}

// binned fill straight from ei: packed records (r | c_local<<16) grouped by bucket.
__global__ void k_bin(const void* ei, const int* flag,
                      int* __restrict__ bcur, unsigned* __restrict__ binned) {
    __shared__ int hist[NBK];
    __shared__ int gbase[NBK];
    const int base = blockIdx.x * CHUNK;
    for (int i = threadIdx.x; i < NBK; i += 256) hist[i] = 0;
    __syncthreads();
    const int w64 = *flag;
    int myr[PERT], myc[PERT];
#pragma unroll
    for (int i = 0; i < PERT; ++i) {
        int idx = base + threadIdx.x + i * 256;
        if (idx < NE) {
            myr[i] = ld_col(ei, w64, idx);
            int c = ld_col(ei, w64, (size_t)NE + idx);
            myc[i] = c;
            atomicAdd(&hist[c >> 6], 1);
        } else {
            myc[i] = -1;
        }
    }
    __syncthreads();
    for (int b = threadIdx.x; b < NBK; b += 256) {
        int h = hist[b];
        gbase[b] = h ? atomicAdd(&bcur[b], h) : 0;
        hist[b] = 0;  // reuse as local cursor
    }
    __syncthreads();
#pragma unroll
    for (int i = 0; i < PERT; ++i) {
        int c = myc[i];
        if (c >= 0) {
            int bkt = c >> 6;
            int pos = gbase[bkt] + atomicAdd(&hist[bkt], 1);
            binned[pos] = (unsigned)myr[i] | ((unsigned)(c & 63) << 16);
        }
    }
}

// per-bucket: derive per-node offsets (LDS hist + scan), write off[], scatter src[]
__global__ void k_sort(const int* __restrict__ boff, const unsigned* __restrict__ binned,
                       int* __restrict__ off, int* __restrict__ src) {
    __shared__ int hcnt[BSTEP];
    __shared__ int sc[BSTEP];
    __shared__ int hoff[BSTEP];
    __shared__ int cur[BSTEP];
    const int b = blockIdx.x;
    const int nbase = b * BSTEP;
    const int p0 = boff[b], p1 = boff[b + 1];
    if (threadIdx.x < BSTEP) hcnt[threadIdx.x] = 0;
    __syncthreads();
    // pass 1: per-node counts
    for (int p = p0 + threadIdx.x; p < p1; p += 256)
        atomicAdd(&hcnt[binned[p] >> 16], 1);
    __syncthreads();
    int v = 0;
    if (threadIdx.x < BSTEP) { v = hcnt[threadIdx.x]; sc[threadIdx.x] = v; }
    __syncthreads();
    for (int d = 1; d < BSTEP; d <<= 1) {
        int u = 0;
        if (threadIdx.x < BSTEP && threadIdx.x >= d) u = sc[threadIdx.x - d];
        __syncthreads();
        if (threadIdx.x < BSTEP) sc[threadIdx.x] += u;
        __syncthreads();
    }
    if (threadIdx.x < BSTEP) {
        int o = p0 + sc[threadIdx.x] - v;  // exclusive
        hoff[threadIdx.x] = o;
        cur[threadIdx.x] = 0;
        int n = nbase + threadIdx.x;
        if (n < NN) off[n] = o;
    }
    __syncthreads();
    // pass 2: scatter grouped by node
    for (int p = p0 + threadIdx.x; p < p1; p += 256) {
        unsigned rec = binned[p];
        int cl = rec >> 16;
        int pos = hoff[cl] + atomicAdd(&cur[cl], 1);
        src[pos] = (int)(rec & 0xffffu);
    }
}

// hs16[n*32+k] = bf16(dinv[n] * dot(x[n,:], W[:,k])) ; 20 lanes per node (64B rows)
__global__ void k_xw(const float* __restrict__ x, const float* __restrict__ W,
                     const int* __restrict__ off, __hip_bfloat16* __restrict__ hs16) {
    int t = blockIdx.x * blockDim.x + threadIdx.x;
    int n = t / EH;
    int k = t - n * EH;
    if (n >= NN) return;
    const float4* xr = (const float4*)(x + (size_t)n * FIN);
    float acc = 0.f;
#pragma unroll
    for (int j4 = 0; j4 < FIN / 4; ++j4) {
        float4 v = xr[j4];  // broadcast across the 20-lane group
        acc = fmaf(v.x, W[(4 * j4 + 0) * EH + k], acc);
        acc = fmaf(v.y, W[(4 * j4 + 1) * EH + k], acc);
        acc = fmaf(v.z, W[(4 * j4 + 2) * EH + k], acc);
        acc = fmaf(v.w, W[(4 * j4 + 3) * EH + k], acc);
    }
    float dinv = rsqrtf(1.0f + (float)(off[n + 1] - off[n]));
    hs16[n * 32 + k] = __float2bfloat16(dinv * acc);
}

__device__ __forceinline__ float blo(unsigned u) { return __uint_as_float(u << 16); }
__device__ __forceinline__ float bhi(unsigned u) { return __uint_as_float(u & 0xffff0000u); }

// per-node gather + bias + relu; 10 lanes per node, each lane owns 2 feature slots
__global__ void k_gather(const int* __restrict__ off, const int* __restrict__ src,
                         const __hip_bfloat16* __restrict__ hs16,
                         const float* __restrict__ bg, float* __restrict__ h1) {
    int t = blockIdx.x * blockDim.x + threadIdx.x;
    int n = t / 10;
    int kk = t - n * 10;     // feature pair index: handles k=2kk, 2kk+1
    if (n >= NN) return;
    const unsigned* hu = (const unsigned*)hs16;  // row stride 16 uints (32 bf16)
    unsigned self = hu[n * 16 + kk];
    float acc0 = blo(self), acc1 = bhi(self);
    int e0 = off[n], e1 = off[n + 1];
    int e = e0;
    for (; e + 1 < e1; e += 2) {
        int r0 = src[e];       // broadcast across group
        int r1 = src[e + 1];
        unsigned v0 = hu[r0 * 16 + kk];
        unsigned v1 = hu[r1 * 16 + kk];
        acc0 += blo(v0); acc1 += bhi(v0);
        acc0 += blo(v1); acc1 += bhi(v1);
    }
    if (e < e1) {
        unsigned v = hu[src[e] * 16 + kk];
        acc0 += blo(v); acc1 += bhi(v);
    }
    float dinv = rsqrtf(1.0f + (float)(e1 - e0));
    float2 res;
    res.x = fmaxf(fmaf(dinv, acc0, bg[2 * kk]), 0.f);
    res.y = fmaxf(fmaf(dinv, acc1, bg[2 * kk + 1]), 0.f);
    *(float2*)(h1 + (size_t)n * EH + 2 * kk) = res;
}

// A16[n,j] = bf16(h1[n,:] @ W1[0:20, j]);
// B16[n,j] = bf16(b1[j] + h1[nid,:] @ W1[40:60, j] + h1[n,:] @ W1[20:40, j])
__global__ void k_ab(const float* __restrict__ h1, const float* __restrict__ W1,
                     const float* __restrict__ b1, const void* nid_p,
                     __hip_bfloat16* __restrict__ A16, __hip_bfloat16* __restrict__ B16) {
    int t = blockIdx.x * blockDim.x + threadIdx.x;
    int n = t >> 6;
    int j = t & 63;
    if (n >= NN) return;
    int nid = *(const int*)nid_p;  // low 32 bits valid for int32 or int64 LE
    const float* hr = h1 + (size_t)n * EH;
    const float* hn = h1 + (size_t)nid * EH;  // broadcast
    float a = 0.f, b = b1[j];
#pragma unroll
    for (int k = 0; k < EH; ++k) {
        float hv = hr[k];
        a = fmaf(hv, W1[k * DH + j], a);
        b = fmaf(hv, W1[(EH + k) * DH + j], b);
        b = fmaf(hn[k], W1[(2 * EH + k) * DH + j], b);
    }
    A16[(size_t)n * DH + j] = __float2bfloat16(a);
    B16[(size_t)n * DH + j] = __float2bfloat16(b);
}

// per-edge decoder: 2 lanes per edge, each lane handles one 64B half of the rows.
__global__ void k_edge(const void* ei, const int* flag,
                       const __hip_bfloat16* __restrict__ A16,
                       const __hip_bfloat16* __restrict__ B16,
                       const float* __restrict__ W2, const float* __restrict__ b2,
                       const float* __restrict__ eps, float* __restrict__ out) {
    int t = blockIdx.x * blockDim.x + threadIdx.x;
    int e = t >> 1;
    if (e >= NE) return;
    int half = t & 1;
    const int w64 = *flag;
    int r = ld_col(ei, w64, e);
    int c = ld_col(ei, w64, (size_t)NE + e);
    const uint4* arow = (const uint4*)(A16 + (size_t)r * DH) + half * 4;
    const uint4* brow = (const uint4*)(B16 + (size_t)c * DH) + half * 4;
    const float* w = W2 + half * 32;
    float acc = 0.f;
#pragma unroll
    for (int j = 0; j < 4; ++j) {
        uint4 av = arow[j];
        uint4 bv = brow[j];
        acc = fmaf(fmaxf(blo(av.x) + blo(bv.x), 0.f), w[8 * j + 0], acc);
        acc = fmaf(fmaxf(bhi(av.x) + bhi(bv.x), 0.f), w[8 * j + 1], acc);
        acc = fmaf(fmaxf(blo(av.y) + blo(bv.y), 0.f), w[8 * j + 2], acc);
        acc = fmaf(fmaxf(bhi(av.y) + bhi(bv.y), 0.f), w[8 * j + 3], acc);
        acc = fmaf(fmaxf(blo(av.z) + blo(bv.z), 0.f), w[8 * j + 4], acc);
        acc = fmaf(fmaxf(bhi(av.z) + bhi(bv.z), 0.f), w[8 * j + 5], acc);
        acc = fmaf(fmaxf(blo(av.w) + blo(bv.w), 0.f), w[8 * j + 6], acc);
        acc = fmaf(fmaxf(bhi(av.w) + bhi(bv.w), 0.f), w[8 * j + 7], acc);
    }
    acc += __shfl_xor(acc, 1);
    if (half == 0) {
        float ep = eps[e];
        // e = (bias-(1-bias))*eps + (1-bias), bias=1e-4
        float ee = fmaf(-0.9998f, ep, 0.9999f);
        float gate = logf(ee) - log1pf(-ee) + acc + b2[0];
        out[e] = 1.0f / (1.0f + expf(-gate));
    }
}

// ---------------- launch ----------------

extern "C" void kernel_launch(void* const* d_in, const int* in_sizes, int n_in,
                              void* d_out, int out_size, void* d_ws, size_t ws_size,
                              hipStream_t stream) {
    const float* x   = (const float*)d_in[0];
    const void*  ei  = d_in[1];
    const void*  nid = d_in[2];
    const float* eps = (const float*)d_in[3];
    const float* Wg  = (const float*)d_in[4];
    const float* bg  = (const float*)d_in[5];
    const float* W1  = (const float*)d_in[6];
    const float* b1  = (const float*)d_in[7];
    const float* W2  = (const float*)d_in[8];
    const float* b2  = (const float*)d_in[9];
    float* out = (float*)d_out;

    float* ws = (float*)d_ws;
    // Total ~8.4M floats ≈ 33 MB, no aliasing.
    unsigned* binned = (unsigned*)(ws + 0);                   // 1.6M
    int*  src    = (int*)(ws + 1600000);                      // 1.6M
    __hip_bfloat16* hs16 = (__hip_bfloat16*)(ws + 3200000);   // 0.8M floats
    float* h1    = ws + 4000000;                              // 1.0M
    __hip_bfloat16* A16 = (__hip_bfloat16*)(ws + 5000000);    // 1.6M floats
    __hip_bfloat16* B16 = (__hip_bfloat16*)(ws + 6600000);    // 1.6M floats
    int* off     = (int*)(ws + 8200000);                      // NN+1
    int* boff    = (int*)(ws + 8260000);                      // NBK+1
    int* bcur    = (int*)(ws + 8262000);                      // NBK
    int* bcnt    = (int*)(ws + 8264000);                      // NBK
    int* flag    = (int*)(ws + 8266000);

    dim3 blk(256);
    const int nchunk = (NE + CHUNK - 1) / CHUNK;
    k_init<<<1, 1024, 0, stream>>>(bcnt, flag, ei);
    k_cnt<<<nchunk, blk, 0, stream>>>(ei, flag, bcnt);
    k_bscan<<<1, 1024, 0, stream>>>(bcnt, boff, bcur, off);
    k_bin<<<nchunk, blk, 0, stream>>>(ei, flag, bcur, binned);
    k_sort<<<NBK, blk, 0, stream>>>(boff, binned, off, src);
    k_xw<<<(NN * EH + 255) / 256, blk, 0, stream>>>(x, Wg, off, hs16);
    k_gather<<<(NN * 10 + 255) / 256, blk, 0, stream>>>(off, src, hs16, bg, h1);
    k_ab<<<(NN * 64 + 255) / 256, blk, 0, stream>>>(h1, W1, b1, nid, A16, B16);
    k_edge<<<((size_t)NE * 2 + 255) / 256, blk, 0, stream>>>(ei, flag, A16, B16, W2, b2, eps, out);
}

// Round 12
// 194.552 us; speedup vs baseline: 2.8682x; 1.0776x over previous
//
#include <hip/hip_runtime.h>
#include <hip/hip_bf16.h>
#include <math.h>

#define NN 50000
#define NE 1600000
#define FIN 128
#define EH 20
#define DH 64

#define BSTEP 64                        // nodes per bucket
#define NBK ((NN + BSTEP - 1) / BSTEP)  // 782 buckets
#define CHUNK 4096                      // edges per counting/binning block
#define PERT (CHUNK / 256)              // 16 edges per thread

// ---------------- kernels ----------------

// zero bucket counters and detect edge_index width (int64 vs int32)
__global__ void k_init(int* bcnt, int* flag, const void* ei) {
    int i = threadIdx.x;
    for (int b = i; b < NBK; b += 1024) bcnt[b] = 0;
    if (i == 0) {
        const int* w = (const int*)ei;
        int all0 = 1;
        for (int j = 1; j < 128; j += 2) all0 &= (w[j] == 0);
        *flag = all0;  // 1 => int64 layout (high words zero), 0 => int32
    }
}

__device__ __forceinline__ int ld_col(const void* ei, int w64, size_t idx) {
    return w64 ? (int)((const long long*)ei)[idx] : ((const int*)ei)[idx];
}

// count edges per 64-node bucket (LDS histogram, few global atomics)
__global__ void k_cnt(const void* ei, const int* flag, int* bcnt) {
    __shared__ int hist[NBK];
    for (int i = threadIdx.x; i < NBK; i += 256) hist[i] = 0;
    __syncthreads();
    const int base = blockIdx.x * CHUNK;
    const int w64 = *flag;
#pragma unroll
    for (int i = 0; i < PERT; ++i) {
        int idx = base + threadIdx.x + i * 256;
        if (idx < NE) {
            int c = ld_col(ei, w64, (size_t)NE + idx);
            atomicAdd(&hist[c >> 6], 1);
        }
    }
    __syncthreads();
    for (int b = threadIdx.x; b < NBK; b += 256)
        if (hist[b]) atomicAdd(&bcnt[b], hist[b]);
}

// single-block exclusive scan of bucket counts -> boff, bcur
__global__ void k_bscan(const int* __restrict__ bcnt, int* __restrict__ boff,
                        int* __restrict__ bcur, int* __restrict__ off) {
    __shared__ int s[1024];
    int t = threadIdx.x;
    int v = (t < NBK) ? bcnt[t] : 0;
    s[t] = v;
    __syncthreads();
    for (int d = 1; d < 1024; d <<= 1) {
        int u = (t >= d) ? s[t - d] : 0;
        __syncthreads();
        s[t] += u;
        __syncthreads();
    }
    if (t < NBK) {
        int e = s[t] - v;  // exclusive prefix
        boff[t] = e;
        bcur[t] = e;
    }
    if (t == 0) { boff[NBK] = NE; off[NN] = NE; }
}

// binned fill straight from ei: packed records (r | c_local<<16) grouped by bucket.
__global__ void k_bin(const void* ei, const int* flag,
                      int* __restrict__ bcur, unsigned* __restrict__ binned) {
    __shared__ int hist[NBK];
    __shared__ int gbase[NBK];
    const int base = blockIdx.x * CHUNK;
    for (int i = threadIdx.x; i < NBK; i += 256) hist[i] = 0;
    __syncthreads();
    const int w64 = *flag;
    int myr[PERT], myc[PERT];
#pragma unroll
    for (int i = 0; i < PERT; ++i) {
        int idx = base + threadIdx.x + i * 256;
        if (idx < NE) {
            myr[i] = ld_col(ei, w64, idx);
            int c = ld_col(ei, w64, (size_t)NE + idx);
            myc[i] = c;
            atomicAdd(&hist[c >> 6], 1);
        } else {
            myc[i] = -1;
        }
    }
    __syncthreads();
    for (int b = threadIdx.x; b < NBK; b += 256) {
        int h = hist[b];
        gbase[b] = h ? atomicAdd(&bcur[b], h) : 0;
        hist[b] = 0;  // reuse as local cursor
    }
    __syncthreads();
#pragma unroll
    for (int i = 0; i < PERT; ++i) {
        int c = myc[i];
        if (c >= 0) {
            int bkt = c >> 6;
            int pos = gbase[bkt] + atomicAdd(&hist[bkt], 1);
            binned[pos] = (unsigned)myr[i] | ((unsigned)(c & 63) << 16);
        }
    }
}

// per-bucket: derive per-node offsets (LDS hist + scan), write off[], scatter src[]
__global__ void k_sort(const int* __restrict__ boff, const unsigned* __restrict__ binned,
                       int* __restrict__ off, int* __restrict__ src) {
    __shared__ int hcnt[BSTEP];
    __shared__ int sc[BSTEP];
    __shared__ int hoff[BSTEP];
    __shared__ int cur[BSTEP];
    const int b = blockIdx.x;
    const int nbase = b * BSTEP;
    const int p0 = boff[b], p1 = boff[b + 1];
    if (threadIdx.x < BSTEP) hcnt[threadIdx.x] = 0;
    __syncthreads();
    // pass 1: per-node counts
    for (int p = p0 + threadIdx.x; p < p1; p += 256)
        atomicAdd(&hcnt[binned[p] >> 16], 1);
    __syncthreads();
    int v = 0;
    if (threadIdx.x < BSTEP) { v = hcnt[threadIdx.x]; sc[threadIdx.x] = v; }
    __syncthreads();
    for (int d = 1; d < BSTEP; d <<= 1) {
        int u = 0;
        if (threadIdx.x < BSTEP && threadIdx.x >= d) u = sc[threadIdx.x - d];
        __syncthreads();
        if (threadIdx.x < BSTEP) sc[threadIdx.x] += u;
        __syncthreads();
    }
    if (threadIdx.x < BSTEP) {
        int o = p0 + sc[threadIdx.x] - v;  // exclusive
        hoff[threadIdx.x] = o;
        cur[threadIdx.x] = 0;
        int n = nbase + threadIdx.x;
        if (n < NN) off[n] = o;
    }
    __syncthreads();
    // pass 2: scatter grouped by node
    for (int p = p0 + threadIdx.x; p < p1; p += 256) {
        unsigned rec = binned[p];
        int cl = rec >> 16;
        int pos = hoff[cl] + atomicAdd(&cur[cl], 1);
        src[pos] = (int)(rec & 0xffffu);
    }
}

// hs16[n*32+k] = bf16(dinv[n] * dot(x[n,:], W[:,k])) ; 20 lanes per node (64B rows)
__global__ void k_xw(const float* __restrict__ x, const float* __restrict__ W,
                     const int* __restrict__ off, __hip_bfloat16* __restrict__ hs16) {
    int t = blockIdx.x * blockDim.x + threadIdx.x;
    int n = t / EH;
    int k = t - n * EH;
    if (n >= NN) return;
    const float4* xr = (const float4*)(x + (size_t)n * FIN);
    float acc = 0.f;
#pragma unroll
    for (int j4 = 0; j4 < FIN / 4; ++j4) {
        float4 v = xr[j4];  // broadcast across the 20-lane group
        acc = fmaf(v.x, W[(4 * j4 + 0) * EH + k], acc);
        acc = fmaf(v.y, W[(4 * j4 + 1) * EH + k], acc);
        acc = fmaf(v.z, W[(4 * j4 + 2) * EH + k], acc);
        acc = fmaf(v.w, W[(4 * j4 + 3) * EH + k], acc);
    }
    float dinv = rsqrtf(1.0f + (float)(off[n + 1] - off[n]));
    hs16[n * 32 + k] = __float2bfloat16(dinv * acc);
}

__device__ __forceinline__ float blo(unsigned u) { return __uint_as_float(u << 16); }
__device__ __forceinline__ float bhi(unsigned u) { return __uint_as_float(u & 0xffff0000u); }

// per-node gather + bias + relu; 10 lanes per node, each lane owns 2 feature slots
__global__ void k_gather(const int* __restrict__ off, const int* __restrict__ src,
                         const __hip_bfloat16* __restrict__ hs16,
                         const float* __restrict__ bg, float* __restrict__ h1) {
    int t = blockIdx.x * blockDim.x + threadIdx.x;
    int n = t / 10;
    int kk = t - n * 10;     // feature pair index: handles k=2kk, 2kk+1
    if (n >= NN) return;
    const unsigned* hu = (const unsigned*)hs16;  // row stride 16 uints (32 bf16)
    unsigned self = hu[n * 16 + kk];
    float acc0 = blo(self), acc1 = bhi(self);
    int e0 = off[n], e1 = off[n + 1];
    int e = e0;
    for (; e + 1 < e1; e += 2) {
        int r0 = src[e];       // broadcast across group
        int r1 = src[e + 1];
        unsigned v0 = hu[r0 * 16 + kk];
        unsigned v1 = hu[r1 * 16 + kk];
        acc0 += blo(v0); acc1 += bhi(v0);
        acc0 += blo(v1); acc1 += bhi(v1);
    }
    if (e < e1) {
        unsigned v = hu[src[e] * 16 + kk];
        acc0 += blo(v); acc1 += bhi(v);
    }
    float dinv = rsqrtf(1.0f + (float)(e1 - e0));
    float2 res;
    res.x = fmaxf(fmaf(dinv, acc0, bg[2 * kk]), 0.f);
    res.y = fmaxf(fmaf(dinv, acc1, bg[2 * kk + 1]), 0.f);
    *(float2*)(h1 + (size_t)n * EH + 2 * kk) = res;
}

// A16[n,j] = bf16(h1[n,:] @ W1[0:20, j]);
// B16[n,j] = bf16(b1[j] + h1[nid,:] @ W1[40:60, j] + h1[n,:] @ W1[20:40, j])
__global__ void k_ab(const float* __restrict__ h1, const float* __restrict__ W1,
                     const float* __restrict__ b1, const void* nid_p,
                     __hip_bfloat16* __restrict__ A16, __hip_bfloat16* __restrict__ B16) {
    int t = blockIdx.x * blockDim.x + threadIdx.x;
    int n = t >> 6;
    int j = t & 63;
    if (n >= NN) return;
    int nid = *(const int*)nid_p;  // low 32 bits valid for int32 or int64 LE
    const float* hr = h1 + (size_t)n * EH;
    const float* hn = h1 + (size_t)nid * EH;  // broadcast
    float a = 0.f, b = b1[j];
#pragma unroll
    for (int k = 0; k < EH; ++k) {
        float hv = hr[k];
        a = fmaf(hv, W1[k * DH + j], a);
        b = fmaf(hv, W1[(EH + k) * DH + j], b);
        b = fmaf(hn[k], W1[(2 * EH + k) * DH + j], b);
    }
    A16[(size_t)n * DH + j] = __float2bfloat16(a);
    B16[(size_t)n * DH + j] = __float2bfloat16(b);
}

// per-edge decoder: 4 lanes per edge, each lane handles one 32B quarter of the rows.
__global__ void k_edge(const void* ei, const int* flag,
                       const __hip_bfloat16* __restrict__ A16,
                       const __hip_bfloat16* __restrict__ B16,
                       const float* __restrict__ W2, const float* __restrict__ b2,
                       const float* __restrict__ eps, float* __restrict__ out) {
    long long t = (long long)blockIdx.x * blockDim.x + threadIdx.x;
    int e = (int)(t >> 2);
    if (e >= NE) return;
    int q = (int)(t & 3);
    const int w64 = *flag;
    int r = ld_col(ei, w64, e);
    int c = ld_col(ei, w64, (size_t)NE + e);
    const uint4* arow = (const uint4*)(A16 + (size_t)r * DH) + q * 2;
    const uint4* brow = (const uint4*)(B16 + (size_t)c * DH) + q * 2;
    const float* w = W2 + q * 16;
    float acc = 0.f;
#pragma unroll
    for (int j = 0; j < 2; ++j) {
        uint4 av = arow[j];
        uint4 bv = brow[j];
        acc = fmaf(fmaxf(blo(av.x) + blo(bv.x), 0.f), w[8 * j + 0], acc);
        acc = fmaf(fmaxf(bhi(av.x) + bhi(bv.x), 0.f), w[8 * j + 1], acc);
        acc = fmaf(fmaxf(blo(av.y) + blo(bv.y), 0.f), w[8 * j + 2], acc);
        acc = fmaf(fmaxf(bhi(av.y) + bhi(bv.y), 0.f), w[8 * j + 3], acc);
        acc = fmaf(fmaxf(blo(av.z) + blo(bv.z), 0.f), w[8 * j + 4], acc);
        acc = fmaf(fmaxf(bhi(av.z) + bhi(bv.z), 0.f), w[8 * j + 5], acc);
        acc = fmaf(fmaxf(blo(av.w) + blo(bv.w), 0.f), w[8 * j + 6], acc);
        acc = fmaf(fmaxf(bhi(av.w) + bhi(bv.w), 0.f), w[8 * j + 7], acc);
    }
    acc += __shfl_xor(acc, 1);
    acc += __shfl_xor(acc, 2);
    if (q == 0) {
        float ep = eps[e];
        // ee = 0.9999 - 0.9998*ep ; 1-ee = 1e-4 + 0.9998*ep
        float ee = fmaf(-0.9998f, ep, 0.9999f);
        float om = fmaf(0.9998f, ep, 0.0001f);
        // logit(ee) = ln2 * (log2(ee) - log2(1-ee))  [v_log_f32]
        float gate = 0.69314718f * (__builtin_amdgcn_logf(ee) - __builtin_amdgcn_logf(om))
                   + acc + b2[0];
        // sigmoid via HW exp2 + fast rcp
        float tt = __builtin_amdgcn_exp2f(-1.44269504f * gate);
        out[e] = __builtin_amdgcn_rcpf(1.0f + tt);
    }
}

// ---------------- launch ----------------

extern "C" void kernel_launch(void* const* d_in, const int* in_sizes, int n_in,
                              void* d_out, int out_size, void* d_ws, size_t ws_size,
                              hipStream_t stream) {
    const float* x   = (const float*)d_in[0];
    const void*  ei  = d_in[1];
    const void*  nid = d_in[2];
    const float* eps = (const float*)d_in[3];
    const float* Wg  = (const float*)d_in[4];
    const float* bg  = (const float*)d_in[5];
    const float* W1  = (const float*)d_in[6];
    const float* b1  = (const float*)d_in[7];
    const float* W2  = (const float*)d_in[8];
    const float* b2  = (const float*)d_in[9];
    float* out = (float*)d_out;

    float* ws = (float*)d_ws;
    // Total ~8.4M floats ≈ 33 MB, no aliasing.
    unsigned* binned = (unsigned*)(ws + 0);                   // 1.6M
    int*  src    = (int*)(ws + 1600000);                      // 1.6M
    __hip_bfloat16* hs16 = (__hip_bfloat16*)(ws + 3200000);   // 0.8M floats
    float* h1    = ws + 4000000;                              // 1.0M
    __hip_bfloat16* A16 = (__hip_bfloat16*)(ws + 5000000);    // 1.6M floats
    __hip_bfloat16* B16 = (__hip_bfloat16*)(ws + 6600000);    // 1.6M floats
    int* off     = (int*)(ws + 8200000);                      // NN+1
    int* boff    = (int*)(ws + 8260000);                      // NBK+1
    int* bcur    = (int*)(ws + 8262000);                      // NBK
    int* bcnt    = (int*)(ws + 8264000);                      // NBK
    int* flag    = (int*)(ws + 8266000);

    dim3 blk(256);
    const int nchunk = (NE + CHUNK - 1) / CHUNK;
    k_init<<<1, 1024, 0, stream>>>(bcnt, flag, ei);
    k_cnt<<<nchunk, blk, 0, stream>>>(ei, flag, bcnt);
    k_bscan<<<1, 1024, 0, stream>>>(bcnt, boff, bcur, off);
    k_bin<<<nchunk, blk, 0, stream>>>(ei, flag, bcur, binned);
    k_sort<<<NBK, blk, 0, stream>>>(boff, binned, off, src);
    k_xw<<<(NN * EH + 255) / 256, blk, 0, stream>>>(x, Wg, off, hs16);
    k_gather<<<(NN * 10 + 255) / 256, blk, 0, stream>>>(off, src, hs16, bg, h1);
    k_ab<<<(NN * 64 + 255) / 256, blk, 0, stream>>>(h1, W1, b1, nid, A16, B16);
    k_edge<<<((size_t)NE * 4 + 255) / 256, blk, 0, stream>>>(ei, flag, A16, B16, W2, b2, eps, out);
}